// Round 13
// baseline (446.553 us; speedup 1.0000x reference)
//
#include <hip/hip_runtime.h>
#include <hip/hip_fp16.h>
#include <math.h>

#define N_NODES 100000
#define N_EDGES 1600000
#define CHUNK 1024
#define NCHUNKS ((N_NODES + CHUNK - 1) / CHUNK)   // 98

union H8 { uint4 u; __half2 h[4]; };

__device__ __forceinline__ float red32(float v) {
    #pragma unroll
    for (int m = 16; m >= 1; m >>= 1) v += __shfl_xor(v, m, 64);
    return v;
}

// ---- non-temporal 16B load/store helpers (2x8B, llvm !nontemporal) ----
__device__ __forceinline__ int4 ntld(const int4* p) {
    const unsigned long long* q = (const unsigned long long*)p;
    unsigned long long a = __builtin_nontemporal_load(q);
    unsigned long long b = __builtin_nontemporal_load(q + 1);
    int4 r;
    r.x = (int)(a & 0xffffffffull); r.y = (int)(a >> 32);
    r.z = (int)(b & 0xffffffffull); r.w = (int)(b >> 32);
    return r;
}
__device__ __forceinline__ float4 ntldf(const float4* p) {
    int4 t = ntld((const int4*)p);
    float4 r;
    r.x = __int_as_float(t.x); r.y = __int_as_float(t.y);
    r.z = __int_as_float(t.z); r.w = __int_as_float(t.w);
    return r;
}
__device__ __forceinline__ void ntst(int4* p, int4 v) {
    unsigned long long a = ((unsigned long long)(unsigned)v.y << 32) | (unsigned)v.x;
    unsigned long long b = ((unsigned long long)(unsigned)v.w << 32) | (unsigned)v.z;
    __builtin_nontemporal_store(a, (unsigned long long*)p);
    __builtin_nontemporal_store(b, ((unsigned long long*)p) + 1);
}

// ---------------- histogram ----------------
__global__ __launch_bounds__(256) void hist(const int* __restrict__ col,
                                            int* __restrict__ cnt) {
    int e = blockIdx.x * blockDim.x + threadIdx.x;
    if (e >= N_EDGES) return;
    int c = __builtin_nontemporal_load(col + e);
    atomicAdd(&cnt[c], 1);
}

// ---------------- scan (3 kernels) ----------------
__global__ void scan_part(const int* __restrict__ cnt, int* __restrict__ psum) {
    __shared__ int sd[CHUNK];
    int i = blockIdx.x * CHUNK + threadIdx.x;
    sd[threadIdx.x] = (i < N_NODES) ? cnt[i] : 0;
    __syncthreads();
    for (int s = CHUNK / 2; s > 0; s >>= 1) {
        if (threadIdx.x < s) sd[threadIdx.x] += sd[threadIdx.x + s];
        __syncthreads();
    }
    if (threadIdx.x == 0) psum[blockIdx.x] = sd[0];
}

__global__ void scan_top(const int* __restrict__ psum, int* __restrict__ coff,
                         int* __restrict__ off) {
    if (blockIdx.x == 0 && threadIdx.x == 0) {
        int run = 0;
        for (int i = 0; i < NCHUNKS; ++i) { coff[i] = run; run += psum[i]; }
        off[N_NODES] = N_EDGES;
    }
}

__global__ void scan_apply(const int* __restrict__ cnt, const int* __restrict__ coff,
                           int* __restrict__ off, int* __restrict__ head) {
    __shared__ int sd[CHUNK];
    int i = blockIdx.x * CHUNK + threadIdx.x;
    int v = (i < N_NODES) ? cnt[i] : 0;
    sd[threadIdx.x] = v;
    __syncthreads();
    for (int s = 1; s < CHUNK; s <<= 1) {
        int t = (threadIdx.x >= s) ? sd[threadIdx.x - s] : 0;
        __syncthreads();
        sd[threadIdx.x] += t;
        __syncthreads();
    }
    if (i < N_NODES) {
        int excl = coff[blockIdx.x] + sd[threadIdx.x] - v;
        off[i] = excl;
        head[i] = excl;
    }
}

// ---- y1h = half(x @ W1[0:128,:]) row-major + nx = |x|^2 fused ----
__global__ __launch_bounds__(256) void gemm_y1h(const float* __restrict__ x,
                                                const float* __restrict__ W1,
                                                __half* __restrict__ y1h,
                                                float* __restrict__ nx) {
    __shared__ float xs[64][129];
    int r0 = blockIdx.x * 64;
    int t = threadIdx.x;
    for (int i = t; i < 64 * 32; i += 256) {
        int rr = i >> 5, c4 = (i & 31) * 4;
        int gr = r0 + rr;
        float4 v = (gr < N_NODES) ? ntldf((const float4*)(x + (size_t)gr * 128 + c4))
                                  : make_float4(0.f, 0.f, 0.f, 0.f);
        xs[rr][c4] = v.x; xs[rr][c4 + 1] = v.y; xs[rr][c4 + 2] = v.z; xs[rr][c4 + 3] = v.w;
    }
    __syncthreads();
    // fused |x|^2
    {
        int rr = t >> 2, q = t & 3;
        float s = 0.f;
        #pragma unroll
        for (int k = 0; k < 32; ++k) { float v = xs[rr][q * 32 + k]; s += v * v; }
        s += __shfl_xor(s, 1, 64);
        s += __shfl_xor(s, 2, 64);
        if (q == 0 && r0 + rr < N_NODES) nx[r0 + rr] = s;
    }
    int tx = t & 31, ty = t >> 5;
    float4 acc[8];
    #pragma unroll
    for (int i = 0; i < 8; ++i) acc[i] = make_float4(0.f, 0.f, 0.f, 0.f);
    #pragma unroll 4
    for (int k = 0; k < 128; ++k) {
        float4 wv = *(const float4*)(W1 + (size_t)k * 128 + tx * 4);
        #pragma unroll
        for (int i = 0; i < 8; ++i) {
            float xv = xs[ty * 8 + i][k];
            acc[i].x += xv * wv.x; acc[i].y += xv * wv.y;
            acc[i].z += xv * wv.z; acc[i].w += xv * wv.w;
        }
    }
    #pragma unroll
    for (int i = 0; i < 8; ++i) {
        int rr = r0 + ty * 8 + i;
        if (rr < N_NODES) {
            H8 pk;
            pk.h[0] = __float22half2_rn(make_float2(acc[i].x, acc[i].y));
            pk.h[1] = __float22half2_rn(make_float2(acc[i].z, acc[i].w));
            *(uint2*)(y1h + (size_t)rr * 128 + tx * 4) = make_uint2(pk.u.x, pk.u.y);
        }
    }
}

// ---- scatter: read ea coalesced (nt), sqea/w1 inline, 16B meta scattered (nt) ----
__global__ __launch_bounds__(256) void scatter_e(
        const int* __restrict__ row, const int* __restrict__ col,
        const float* __restrict__ nx, const float* __restrict__ ea,
        int* __restrict__ head, int4* __restrict__ csrM) {
    int e = blockIdx.x * blockDim.x + threadIdx.x;
    if (e >= N_EDGES) return;
    const float4* p = (const float4*)(ea + (size_t)e * 16);
    float4 q0 = ntldf(p), q1 = ntldf(p + 1), q2 = ntldf(p + 2), q3 = ntldf(p + 3);
    float s = q0.x*q0.x + q0.y*q0.y + q0.z*q0.z + q0.w*q0.w
            + q1.x*q1.x + q1.y*q1.y + q1.z*q1.z + q1.w*q1.w
            + q2.x*q2.x + q2.y*q2.y + q2.z*q2.z + q2.w*q2.w
            + q3.x*q3.x + q3.y*q3.y + q3.z*q3.z + q3.w*q3.w;
    int r = __builtin_nontemporal_load(row + e);
    int c = __builtin_nontemporal_load(col + e);
    float w1 = rsqrtf(fmaxf(nx[r] + s, 1e-24f));   // == 1/max(sqrt(.),1e-12)
    int pp = atomicAdd(&head[c], 1);
    int4 mt; mt.x = r; mt.y = __float_as_int(w1); mt.z = e; mt.w = __float_as_int(s);
    ntst(&csrM[pp], mt);
}

// ---- layer-1 (R9 structure): wave/node; nt on csrM/ea streams, cached y1h ----
__global__ __launch_bounds__(256) void layer1(
        const __half* __restrict__ y1h, const float* __restrict__ ea,
        const int4* __restrict__ csrM, const int* __restrict__ off,
        const float* __restrict__ W1, const float* __restrict__ b1,
        const float* __restrict__ W2, float* __restrict__ hn) {
    __shared__ int4  smeta[4][64];
    __shared__ float strans[4][144];     // [0:128) agg channels, [128:144) sea
    int wv = threadIdx.x >> 6;
    int node = (blockIdx.x << 2) | wv;
    int lane = threadIdx.x & 63;
    if (node >= N_NODES) return;
    int s = off[node], e = off[node + 1];
    int deg = e - s;
    int m = (deg < 64) ? deg : 64;
    if (lane < m) smeta[wv][lane] = ntld(&csrM[s + lane]);
    asm volatile("s_waitcnt lgkmcnt(0)" ::: "memory");   // wave-local LDS fence

    int e4 = lane >> 4;          // edge within quad (4 edges in flight)
    int c8 = lane & 15;          // channel-octet for y1h: ch 8*c8 .. 8*c8+7
    float4 a0 = make_float4(0,0,0,0), a1 = a0;           // y1 agg, 8 ch/lane
    float4 sea = a0;                                     // lanes c8<4: sum w*ea[4c8..]

    #pragma unroll 2
    for (int t = 0; t < m; t += 4) {
        int idx = t + e4;
        bool val = idx < m;
        int4 mt = smeta[wv][val ? idx : 0];
        int r = mt.x;
        float w = val ? __int_as_float(mt.y) : 0.f;
        H8 pk; pk.u = *(const uint4*)(y1h + (size_t)r * 128 + c8 * 8);
        float2 f0 = __half22float2(pk.h[0]);
        float2 f1 = __half22float2(pk.h[1]);
        float2 f2 = __half22float2(pk.h[2]);
        float2 f3 = __half22float2(pk.h[3]);
        a0.x += f0.x * w; a0.y += f0.y * w; a0.z += f1.x * w; a0.w += f1.y * w;
        a1.x += f2.x * w; a1.y += f2.y * w; a1.z += f3.x * w; a1.w += f3.y * w;
        if (c8 < 4) {
            float4 ev = ntldf((const float4*)(ea + (size_t)mt.z * 16 + c8 * 4));
            sea.x += ev.x * w; sea.y += ev.y * w;
            sea.z += ev.z * w; sea.w += ev.w * w;
        }
    }
    for (int t = 64 + e4; t < deg; t += 4) {             // deg>64 fallback (rare)
        int4 mt = ntld(&csrM[s + t]);
        int r = mt.x;
        float w = __int_as_float(mt.y);
        H8 pk; pk.u = *(const uint4*)(y1h + (size_t)r * 128 + c8 * 8);
        float2 f0 = __half22float2(pk.h[0]);
        float2 f1 = __half22float2(pk.h[1]);
        float2 f2 = __half22float2(pk.h[2]);
        float2 f3 = __half22float2(pk.h[3]);
        a0.x += f0.x * w; a0.y += f0.y * w; a0.z += f1.x * w; a0.w += f1.y * w;
        a1.x += f2.x * w; a1.y += f2.y * w; a1.z += f3.x * w; a1.w += f3.y * w;
        if (c8 < 4) {
            float4 ev = ntldf((const float4*)(ea + (size_t)mt.z * 16 + c8 * 4));
            sea.x += ev.x * w; sea.y += ev.y * w;
            sea.z += ev.z * w; sea.w += ev.w * w;
        }
    }
    // reduce across the 4 edge-groups (lane bits 4,5)
    #pragma unroll
    for (int mm = 16; mm <= 32; mm <<= 1) {
        a0.x += __shfl_xor(a0.x, mm, 64); a0.y += __shfl_xor(a0.y, mm, 64);
        a0.z += __shfl_xor(a0.z, mm, 64); a0.w += __shfl_xor(a0.w, mm, 64);
        a1.x += __shfl_xor(a1.x, mm, 64); a1.y += __shfl_xor(a1.y, mm, 64);
        a1.z += __shfl_xor(a1.z, mm, 64); a1.w += __shfl_xor(a1.w, mm, 64);
        sea.x += __shfl_xor(sea.x, mm, 64); sea.y += __shfl_xor(sea.y, mm, 64);
        sea.z += __shfl_xor(sea.z, mm, 64); sea.w += __shfl_xor(sea.w, mm, 64);
    }
    // redistribute through LDS to 32-lane float4 channel layout
    if (e4 == 0) {
        *(float4*)&strans[wv][c8 * 8]     = a0;
        *(float4*)&strans[wv][c8 * 8 + 4] = a1;
        if (c8 < 4) *(float4*)&strans[wv][128 + c8 * 4] = sea;
    }
    asm volatile("s_waitcnt lgkmcnt(0)" ::: "memory");

    int c = lane & 31;                    // channels 4c..4c+3
    float ic = 1.0f / fmaxf((float)deg, 1.0f);
    float4 av = *(const float4*)&strans[wv][c * 4];
    float4 b1v = *(const float4*)(b1 + c * 4);
    float4 o;
    o.x = av.x * ic + b1v.x; o.y = av.y * ic + b1v.y;
    o.z = av.z * ic + b1v.z; o.w = av.w * ic + b1v.w;
    #pragma unroll
    for (int k = 0; k < 16; ++k) {        // edge part @ W1[128+k,:]
        float sk = strans[wv][128 + k] * ic;
        float4 wv4 = *((const float4*)(W1 + (size_t)(128 + k) * 128) + c);
        o.x += sk * wv4.x; o.y += sk * wv4.y; o.z += sk * wv4.z; o.w += sk * wv4.w;
    }
    float ss    = o.x*o.x + o.y*o.y + o.z*o.z + o.w*o.w;
    float sspos = (o.x > 0.f ? o.x*o.x : 0.f) + (o.y > 0.f ? o.y*o.y : 0.f)
                + (o.z > 0.f ? o.z*o.z : 0.f) + (o.w > 0.f ? o.w*o.w : 0.f);
    ss = red32(ss);
    sspos = red32(sspos);
    float inv = rsqrtf(fmaxf(ss, 1e-24f));
    float4 h4;
    h4.x = fmaxf(o.x * inv, 0.f); h4.y = fmaxf(o.y * inv, 0.f);
    h4.z = fmaxf(o.z * inv, 0.f); h4.w = fmaxf(o.w * inv, 0.f);
    float nhv = sspos * inv * inv;        // |relu(h)|^2
    float4 w0 = *(const float4*)(W2 + (size_t)(4*c + 0) * 4);
    float4 w1 = *(const float4*)(W2 + (size_t)(4*c + 1) * 4);
    float4 w2 = *(const float4*)(W2 + (size_t)(4*c + 2) * 4);
    float4 w3 = *(const float4*)(W2 + (size_t)(4*c + 3) * 4);
    float4 p;
    p.x = h4.x*w0.x + h4.y*w1.x + h4.z*w2.x + h4.w*w3.x;
    p.y = h4.x*w0.y + h4.y*w1.y + h4.z*w2.y + h4.w*w3.y;
    p.z = h4.x*w0.z + h4.y*w1.z + h4.z*w2.z + h4.w*w3.z;
    p.w = h4.x*w0.w + h4.y*w1.w + h4.z*w2.w + h4.w*w3.w;
    p.x = red32(p.x); p.y = red32(p.y); p.z = red32(p.z); p.w = red32(p.w);
    if (lane == 0) {
        *(float4*)(hn + (size_t)node * 8) = p;
        hn[(size_t)node * 8 + 4] = nhv;
    }
}

// ---- layer-2: wave/node, 4 lanes/edge x 16 edges; nt csrM/ea; cached hn ----
__global__ __launch_bounds__(256) void layer2(
        const int4* __restrict__ csrM, const float* __restrict__ ea,
        const float* __restrict__ hn, const int* __restrict__ off,
        const float* __restrict__ W2, const float* __restrict__ b2,
        float* __restrict__ out) {
    __shared__ int4 smeta[4][64];
    int wv = threadIdx.x >> 6;
    int node = (blockIdx.x << 2) | wv;
    int lane = threadIdx.x & 63;
    if (node >= N_NODES) return;
    int s = off[node], e = off[node + 1];
    int deg = e - s;
    int m = (deg < 64) ? deg : 64;
    if (lane < m) smeta[wv][lane] = ntld(&csrM[s + lane]);
    asm volatile("s_waitcnt lgkmcnt(0)" ::: "memory");
    int e16 = lane >> 2, q = lane & 3;   // 16 edges in flight, 4 ch-quads each
    float4 w2r0 = *(const float4*)(W2 + (size_t)(128 + q * 4 + 0) * 4);
    float4 w2r1 = *(const float4*)(W2 + (size_t)(128 + q * 4 + 1) * 4);
    float4 w2r2 = *(const float4*)(W2 + (size_t)(128 + q * 4 + 2) * 4);
    float4 w2r3 = *(const float4*)(W2 + (size_t)(128 + q * 4 + 3) * 4);

    float4 acc = make_float4(0.f, 0.f, 0.f, 0.f);   // sum w2*yh (replicated over q)
    float4 sea = make_float4(0.f, 0.f, 0.f, 0.f);   // sum w2*ea[4q..4q+3]
    for (int t = e16; t < m; t += 16) {
        int4 mt = smeta[wv][t];
        int r = mt.x;
        float sq = __int_as_float(mt.w);
        float nh = hn[(size_t)r * 8 + 4];
        float w = rsqrtf(fmaxf(nh + sq, 1e-24f));
        float4 yh = *(const float4*)(hn + (size_t)r * 8);
        float4 ev = ntldf((const float4*)(ea + (size_t)mt.z * 16 + q * 4));
        acc.x += w * yh.x; acc.y += w * yh.y; acc.z += w * yh.z; acc.w += w * yh.w;
        sea.x += w * ev.x; sea.y += w * ev.y; sea.z += w * ev.z; sea.w += w * ev.w;
    }
    for (int t = 64 + e16; t < deg; t += 16) {       // deg>64 fallback (rare)
        int4 mt = ntld(&csrM[s + t]);
        int r = mt.x;
        float sq = __int_as_float(mt.w);
        float nh = hn[(size_t)r * 8 + 4];
        float w = rsqrtf(fmaxf(nh + sq, 1e-24f));
        float4 yh = *(const float4*)(hn + (size_t)r * 8);
        float4 ev = ntldf((const float4*)(ea + (size_t)mt.z * 16 + q * 4));
        acc.x += w * yh.x; acc.y += w * yh.y; acc.z += w * yh.z; acc.w += w * yh.w;
        sea.x += w * ev.x; sea.y += w * ev.y; sea.z += w * ev.z; sea.w += w * ev.w;
    }
    // reduce over the 16 edge-groups (lane bits 2..5); q columns stay separate
    #pragma unroll
    for (int mm = 4; mm <= 32; mm <<= 1) {
        acc.x += __shfl_xor(acc.x, mm, 64); acc.y += __shfl_xor(acc.y, mm, 64);
        acc.z += __shfl_xor(acc.z, mm, 64); acc.w += __shfl_xor(acc.w, mm, 64);
        sea.x += __shfl_xor(sea.x, mm, 64); sea.y += __shfl_xor(sea.y, mm, 64);
        sea.z += __shfl_xor(sea.z, mm, 64); sea.w += __shfl_xor(sea.w, mm, 64);
    }
    // per-lane partial of (sea @ W2e) for rows 4q..4q+3
    float4 pv;
    pv.x = sea.x*w2r0.x + sea.y*w2r1.x + sea.z*w2r2.x + sea.w*w2r3.x;
    pv.y = sea.x*w2r0.y + sea.y*w2r1.y + sea.z*w2r2.y + sea.w*w2r3.y;
    pv.z = sea.x*w2r0.z + sea.y*w2r1.z + sea.z*w2r2.z + sea.w*w2r3.z;
    pv.w = sea.x*w2r0.w + sea.y*w2r1.w + sea.z*w2r2.w + sea.w*w2r3.w;
    // combine the 4 q-partials
    #pragma unroll
    for (int mm = 1; mm <= 2; mm <<= 1) {
        pv.x += __shfl_xor(pv.x, mm, 64); pv.y += __shfl_xor(pv.y, mm, 64);
        pv.z += __shfl_xor(pv.z, mm, 64); pv.w += __shfl_xor(pv.w, mm, 64);
    }
    if (lane == 0) {
        float ic = 1.0f / fmaxf((float)deg, 1.0f);
        float4 o;
        o.x = (acc.x + pv.x) * ic + b2[0];
        o.y = (acc.y + pv.y) * ic + b2[1];
        o.z = (acc.z + pv.z) * ic + b2[2];
        o.w = (acc.w + pv.w) * ic + b2[3];
        float ss = o.x*o.x + o.y*o.y + o.z*o.z + o.w*o.w;
        float inv = rsqrtf(fmaxf(ss, 1e-24f));
        float4 res;
        res.x = 1.0f / (1.0f + expf(-(o.x * inv)));
        res.y = 1.0f / (1.0f + expf(-(o.y * inv)));
        res.z = 1.0f / (1.0f + expf(-(o.z * inv)));
        res.w = 1.0f / (1.0f + expf(-(o.w * inv)));
        *(float4*)(out + (size_t)node * 4) = res;
    }
}

// ---------------- launch ----------------
extern "C" void kernel_launch(void* const* d_in, const int* in_sizes, int n_in,
                              void* d_out, int out_size, void* d_ws, size_t ws_size,
                              hipStream_t stream) {
    const float* x   = (const float*)d_in[0];
    const int*   ei  = (const int*)d_in[1];
    const float* ea  = (const float*)d_in[2];
    const float* W1  = (const float*)d_in[3];
    const float* b1  = (const float*)d_in[4];
    const float* W2  = (const float*)d_in[5];
    const float* b2  = (const float*)d_in[6];
    const int* row = ei;
    const int* col = ei + N_EDGES;
    float* out = (float*)d_out;

    char* ws = (char*)d_ws;
    size_t o = 0;
    auto carve = [&](size_t bytes) { char* p = ws + o; o = (o + bytes + 255) & ~(size_t)255; return p; };
    __half* y1h    = (__half*)carve((size_t)N_NODES * 128 * 2);  // 25.6 MB
    int4*   csrM   = (int4*)carve((size_t)N_EDGES * 16);         // 25.6 MB
    int*    cnt    = (int*)carve((size_t)N_NODES * 4);
    int*    off    = (int*)carve((size_t)(N_NODES + 1) * 4);
    int*    head   = (int*)carve((size_t)N_NODES * 4);
    float*  nx     = (float*)carve((size_t)N_NODES * 4);
    float*  hn     = (float*)carve((size_t)N_NODES * 8 * 4);     // {yh4, nh, pad3}
    int*    psum   = (int*)carve((size_t)NCHUNKS * 4);
    int*    coff   = (int*)carve((size_t)NCHUNKS * 4);
    (void)ws_size; (void)in_sizes; (void)n_in; (void)out_size;

    hipMemsetAsync(cnt, 0, (size_t)N_NODES * 4, stream);

    dim3 b256(256);
    hist<<<(N_EDGES + 255) / 256, b256, 0, stream>>>(col, cnt);
    gemm_y1h<<<(N_NODES + 63) / 64, b256, 0, stream>>>(x, W1, y1h, nx);

    scan_part<<<NCHUNKS, CHUNK, 0, stream>>>(cnt, psum);
    scan_top<<<1, 64, 0, stream>>>(psum, coff, off);
    scan_apply<<<NCHUNKS, CHUNK, 0, stream>>>(cnt, coff, off, head);
    scatter_e<<<(N_EDGES + 255) / 256, b256, 0, stream>>>(row, col, nx, ea, head, csrM);

    layer1<<<(N_NODES + 3) / 4, b256, 0, stream>>>(y1h, ea, csrM, off, W1, b1, W2, hn);
    layer2<<<(N_NODES + 3) / 4, b256, 0, stream>>>(csrM, ea, hn, off, W2, b2, out);
}

// Round 14
// 384.336 us; speedup vs baseline: 1.1619x; 1.1619x over previous
//
#include <hip/hip_runtime.h>
#include <hip/hip_fp16.h>
#include <math.h>

#define N_NODES 100000
#define N_EDGES 1600000
#define CHUNK 1024
#define NCHUNKS ((N_NODES + CHUNK - 1) / CHUNK)   // 98

union H8 { uint4 u; __half2 h[4]; };

__device__ __forceinline__ float red32(float v) {
    #pragma unroll
    for (int m = 16; m >= 1; m >>= 1) v += __shfl_xor(v, m, 64);
    return v;
}

// ---------------- histogram ----------------
__global__ __launch_bounds__(256) void hist(const int* __restrict__ col,
                                            int* __restrict__ cnt) {
    int e = blockIdx.x * blockDim.x + threadIdx.x;
    if (e >= N_EDGES) return;
    atomicAdd(&cnt[col[e]], 1);
}

// ---------------- scan (3 kernels) ----------------
__global__ void scan_part(const int* __restrict__ cnt, int* __restrict__ psum) {
    __shared__ int sd[CHUNK];
    int i = blockIdx.x * CHUNK + threadIdx.x;
    sd[threadIdx.x] = (i < N_NODES) ? cnt[i] : 0;
    __syncthreads();
    for (int s = CHUNK / 2; s > 0; s >>= 1) {
        if (threadIdx.x < s) sd[threadIdx.x] += sd[threadIdx.x + s];
        __syncthreads();
    }
    if (threadIdx.x == 0) psum[blockIdx.x] = sd[0];
}

__global__ void scan_top(const int* __restrict__ psum, int* __restrict__ coff,
                         int* __restrict__ off) {
    if (blockIdx.x == 0 && threadIdx.x == 0) {
        int run = 0;
        for (int i = 0; i < NCHUNKS; ++i) { coff[i] = run; run += psum[i]; }
        off[N_NODES] = N_EDGES;
    }
}

__global__ void scan_apply(const int* __restrict__ cnt, const int* __restrict__ coff,
                           int* __restrict__ off, int* __restrict__ head) {
    __shared__ int sd[CHUNK];
    int i = blockIdx.x * CHUNK + threadIdx.x;
    int v = (i < N_NODES) ? cnt[i] : 0;
    sd[threadIdx.x] = v;
    __syncthreads();
    for (int s = 1; s < CHUNK; s <<= 1) {
        int t = (threadIdx.x >= s) ? sd[threadIdx.x - s] : 0;
        __syncthreads();
        sd[threadIdx.x] += t;
        __syncthreads();
    }
    if (i < N_NODES) {
        int excl = coff[blockIdx.x] + sd[threadIdx.x] - v;
        off[i] = excl;
        head[i] = excl;
    }
}

// ---- y1h = half(x @ W1[0:128,:]) row-major + nx = |x|^2 fused ----
__global__ __launch_bounds__(256) void gemm_y1h(const float* __restrict__ x,
                                                const float* __restrict__ W1,
                                                __half* __restrict__ y1h,
                                                float* __restrict__ nx) {
    __shared__ float xs[64][129];
    int r0 = blockIdx.x * 64;
    int t = threadIdx.x;
    for (int i = t; i < 64 * 32; i += 256) {
        int rr = i >> 5, c4 = (i & 31) * 4;
        int gr = r0 + rr;
        float4 v = (gr < N_NODES) ? *(const float4*)(x + (size_t)gr * 128 + c4)
                                  : make_float4(0.f, 0.f, 0.f, 0.f);
        xs[rr][c4] = v.x; xs[rr][c4 + 1] = v.y; xs[rr][c4 + 2] = v.z; xs[rr][c4 + 3] = v.w;
    }
    __syncthreads();
    // fused |x|^2
    {
        int rr = t >> 2, q = t & 3;
        float s = 0.f;
        #pragma unroll
        for (int k = 0; k < 32; ++k) { float v = xs[rr][q * 32 + k]; s += v * v; }
        s += __shfl_xor(s, 1, 64);
        s += __shfl_xor(s, 2, 64);
        if (q == 0 && r0 + rr < N_NODES) nx[r0 + rr] = s;
    }
    int tx = t & 31, ty = t >> 5;
    float4 acc[8];
    #pragma unroll
    for (int i = 0; i < 8; ++i) acc[i] = make_float4(0.f, 0.f, 0.f, 0.f);
    #pragma unroll 4
    for (int k = 0; k < 128; ++k) {
        float4 wv = *(const float4*)(W1 + (size_t)k * 128 + tx * 4);
        #pragma unroll
        for (int i = 0; i < 8; ++i) {
            float xv = xs[ty * 8 + i][k];
            acc[i].x += xv * wv.x; acc[i].y += xv * wv.y;
            acc[i].z += xv * wv.z; acc[i].w += xv * wv.w;
        }
    }
    #pragma unroll
    for (int i = 0; i < 8; ++i) {
        int rr = r0 + ty * 8 + i;
        if (rr < N_NODES) {
            H8 pk;
            pk.h[0] = __float22half2_rn(make_float2(acc[i].x, acc[i].y));
            pk.h[1] = __float22half2_rn(make_float2(acc[i].z, acc[i].w));
            *(uint2*)(y1h + (size_t)rr * 128 + tx * 4) = make_uint2(pk.u.x, pk.u.y);
        }
    }
}

// ---- scatter: read ea coalesced, sqea/w1 inline, one 16B meta per edge ----
__global__ __launch_bounds__(256) void scatter_e(
        const int* __restrict__ row, const int* __restrict__ col,
        const float* __restrict__ nx, const float* __restrict__ ea,
        int* __restrict__ head, int4* __restrict__ csrM) {
    int e = blockIdx.x * blockDim.x + threadIdx.x;
    if (e >= N_EDGES) return;
    const float4* p = (const float4*)(ea + (size_t)e * 16);
    float4 q0 = p[0], q1 = p[1], q2 = p[2], q3 = p[3];
    float s = q0.x*q0.x + q0.y*q0.y + q0.z*q0.z + q0.w*q0.w
            + q1.x*q1.x + q1.y*q1.y + q1.z*q1.z + q1.w*q1.w
            + q2.x*q2.x + q2.y*q2.y + q2.z*q2.z + q2.w*q2.w
            + q3.x*q3.x + q3.y*q3.y + q3.z*q3.z + q3.w*q3.w;
    int r = row[e];
    int c = col[e];
    float w1 = rsqrtf(fmaxf(nx[r] + s, 1e-24f));   // == 1/max(sqrt(.),1e-12)
    int pp = atomicAdd(&head[c], 1);
    int4 mt; mt.x = r; mt.y = __float_as_int(w1); mt.z = e; mt.w = __float_as_int(s);
    csrM[pp] = mt;
}

// ---- layer-1: wave/node; y1h quad-gather + fp32 ea (sea1 only); fused epilogue ----
__global__ __launch_bounds__(256) void layer1(
        const __half* __restrict__ y1h, const float* __restrict__ ea,
        const int4* __restrict__ csrM, const int* __restrict__ off,
        const float* __restrict__ W1, const float* __restrict__ b1,
        const float* __restrict__ W2, float* __restrict__ hn) {
    __shared__ int4  smeta[4][64];
    __shared__ float strans[4][144];     // [0:128) agg channels, [128:144) sea
    int wv = threadIdx.x >> 6;
    int node = (blockIdx.x << 2) | wv;
    int lane = threadIdx.x & 63;
    if (node >= N_NODES) return;
    int s = off[node], e = off[node + 1];
    int deg = e - s;
    int m = (deg < 64) ? deg : 64;
    if (lane < m) smeta[wv][lane] = csrM[s + lane];
    asm volatile("s_waitcnt lgkmcnt(0)" ::: "memory");   // wave-local LDS fence

    int e4 = lane >> 4;          // edge within quad (4 edges in flight)
    int c8 = lane & 15;          // channel-octet for y1h: ch 8*c8 .. 8*c8+7
    float4 a0 = make_float4(0,0,0,0), a1 = a0;           // y1 agg, 8 ch/lane
    float4 sea = a0;                                     // lanes c8<4: sum w*ea[4c8..]

    #pragma unroll 2
    for (int t = 0; t < m; t += 4) {
        int idx = t + e4;
        bool val = idx < m;
        int4 mt = smeta[wv][val ? idx : 0];
        int r = mt.x;
        float w = val ? __int_as_float(mt.y) : 0.f;
        H8 pk; pk.u = *(const uint4*)(y1h + (size_t)r * 128 + c8 * 8);
        float2 f0 = __half22float2(pk.h[0]);
        float2 f1 = __half22float2(pk.h[1]);
        float2 f2 = __half22float2(pk.h[2]);
        float2 f3 = __half22float2(pk.h[3]);
        a0.x += f0.x * w; a0.y += f0.y * w; a0.z += f1.x * w; a0.w += f1.y * w;
        a1.x += f2.x * w; a1.y += f2.y * w; a1.z += f3.x * w; a1.w += f3.y * w;
        if (c8 < 4) {
            float4 ev = *(const float4*)(ea + (size_t)mt.z * 16 + c8 * 4);
            sea.x += ev.x * w; sea.y += ev.y * w;
            sea.z += ev.z * w; sea.w += ev.w * w;
        }
    }
    for (int t = 64 + e4; t < deg; t += 4) {             // deg>64 fallback (rare)
        int4 mt = csrM[s + t];
        int r = mt.x;
        float w = __int_as_float(mt.y);
        H8 pk; pk.u = *(const uint4*)(y1h + (size_t)r * 128 + c8 * 8);
        float2 f0 = __half22float2(pk.h[0]);
        float2 f1 = __half22float2(pk.h[1]);
        float2 f2 = __half22float2(pk.h[2]);
        float2 f3 = __half22float2(pk.h[3]);
        a0.x += f0.x * w; a0.y += f0.y * w; a0.z += f1.x * w; a0.w += f1.y * w;
        a1.x += f2.x * w; a1.y += f2.y * w; a1.z += f3.x * w; a1.w += f3.y * w;
        if (c8 < 4) {
            float4 ev = *(const float4*)(ea + (size_t)mt.z * 16 + c8 * 4);
            sea.x += ev.x * w; sea.y += ev.y * w;
            sea.z += ev.z * w; sea.w += ev.w * w;
        }
    }
    // reduce across the 4 edge-groups (lane bits 4,5)
    #pragma unroll
    for (int mm = 16; mm <= 32; mm <<= 1) {
        a0.x += __shfl_xor(a0.x, mm, 64); a0.y += __shfl_xor(a0.y, mm, 64);
        a0.z += __shfl_xor(a0.z, mm, 64); a0.w += __shfl_xor(a0.w, mm, 64);
        a1.x += __shfl_xor(a1.x, mm, 64); a1.y += __shfl_xor(a1.y, mm, 64);
        a1.z += __shfl_xor(a1.z, mm, 64); a1.w += __shfl_xor(a1.w, mm, 64);
        sea.x += __shfl_xor(sea.x, mm, 64); sea.y += __shfl_xor(sea.y, mm, 64);
        sea.z += __shfl_xor(sea.z, mm, 64); sea.w += __shfl_xor(sea.w, mm, 64);
    }
    // redistribute through LDS to 32-lane float4 channel layout
    if (e4 == 0) {
        *(float4*)&strans[wv][c8 * 8]     = a0;
        *(float4*)&strans[wv][c8 * 8 + 4] = a1;
        if (c8 < 4) *(float4*)&strans[wv][128 + c8 * 4] = sea;
    }
    asm volatile("s_waitcnt lgkmcnt(0)" ::: "memory");

    int c = lane & 31;                    // channels 4c..4c+3
    float ic = 1.0f / fmaxf((float)deg, 1.0f);
    float4 av = *(const float4*)&strans[wv][c * 4];
    float4 b1v = *(const float4*)(b1 + c * 4);
    float4 o;
    o.x = av.x * ic + b1v.x; o.y = av.y * ic + b1v.y;
    o.z = av.z * ic + b1v.z; o.w = av.w * ic + b1v.w;
    #pragma unroll
    for (int k = 0; k < 16; ++k) {        // edge part @ W1[128+k,:]
        float sk = strans[wv][128 + k] * ic;
        float4 wv4 = *((const float4*)(W1 + (size_t)(128 + k) * 128) + c);
        o.x += sk * wv4.x; o.y += sk * wv4.y; o.z += sk * wv4.z; o.w += sk * wv4.w;
    }
    float ss    = o.x*o.x + o.y*o.y + o.z*o.z + o.w*o.w;
    float sspos = (o.x > 0.f ? o.x*o.x : 0.f) + (o.y > 0.f ? o.y*o.y : 0.f)
                + (o.z > 0.f ? o.z*o.z : 0.f) + (o.w > 0.f ? o.w*o.w : 0.f);
    ss = red32(ss);
    sspos = red32(sspos);
    float inv = rsqrtf(fmaxf(ss, 1e-24f));
    float4 h4;
    h4.x = fmaxf(o.x * inv, 0.f); h4.y = fmaxf(o.y * inv, 0.f);
    h4.z = fmaxf(o.z * inv, 0.f); h4.w = fmaxf(o.w * inv, 0.f);
    float nhv = sspos * inv * inv;        // |relu(h)|^2
    float4 w0 = *(const float4*)(W2 + (size_t)(4*c + 0) * 4);
    float4 w1 = *(const float4*)(W2 + (size_t)(4*c + 1) * 4);
    float4 w2 = *(const float4*)(W2 + (size_t)(4*c + 2) * 4);
    float4 w3 = *(const float4*)(W2 + (size_t)(4*c + 3) * 4);
    float4 p;
    p.x = h4.x*w0.x + h4.y*w1.x + h4.z*w2.x + h4.w*w3.x;
    p.y = h4.x*w0.y + h4.y*w1.y + h4.z*w2.y + h4.w*w3.y;
    p.z = h4.x*w0.z + h4.y*w1.z + h4.z*w2.z + h4.w*w3.z;
    p.w = h4.x*w0.w + h4.y*w1.w + h4.z*w2.w + h4.w*w3.w;
    p.x = red32(p.x); p.y = red32(p.y); p.z = red32(p.z); p.w = red32(p.w);
    if (lane == 0) {
        *(float4*)(hn + (size_t)node * 8) = p;
        hn[(size_t)node * 8 + 4] = nhv;
    }
}

// ---- layer-2: wave/node, 4 lanes/edge x 16 edges; own ea gather; per-node W2e ----
__global__ __launch_bounds__(256) void layer2(
        const int4* __restrict__ csrM, const float* __restrict__ ea,
        const float* __restrict__ hn, const int* __restrict__ off,
        const float* __restrict__ W2, const float* __restrict__ b2,
        float* __restrict__ out) {
    __shared__ int4 smeta[4][64];
    int wv = threadIdx.x >> 6;
    int node = (blockIdx.x << 2) | wv;
    int lane = threadIdx.x & 63;
    if (node >= N_NODES) return;
    int s = off[node], e = off[node + 1];
    int deg = e - s;
    int m = (deg < 64) ? deg : 64;
    if (lane < m) smeta[wv][lane] = csrM[s + lane];
    asm volatile("s_waitcnt lgkmcnt(0)" ::: "memory");
    int e16 = lane >> 2, q = lane & 3;   // 16 edges in flight, 4 ch-quads each
    // this lane's W2e rows: 4q .. 4q+3
    float4 w2r0 = *(const float4*)(W2 + (size_t)(128 + q * 4 + 0) * 4);
    float4 w2r1 = *(const float4*)(W2 + (size_t)(128 + q * 4 + 1) * 4);
    float4 w2r2 = *(const float4*)(W2 + (size_t)(128 + q * 4 + 2) * 4);
    float4 w2r3 = *(const float4*)(W2 + (size_t)(128 + q * 4 + 3) * 4);

    float4 acc = make_float4(0.f, 0.f, 0.f, 0.f);   // sum w2*yh (replicated over q)
    float4 sea = make_float4(0.f, 0.f, 0.f, 0.f);   // sum w2*ea[4q..4q+3]
    for (int t = e16; t < m; t += 16) {
        int4 mt = smeta[wv][t];
        int r = mt.x;
        float sq = __int_as_float(mt.w);
        float nh = hn[(size_t)r * 8 + 4];
        float w = rsqrtf(fmaxf(nh + sq, 1e-24f));
        float4 yh = *(const float4*)(hn + (size_t)r * 8);
        float4 ev = *(const float4*)(ea + (size_t)mt.z * 16 + q * 4);
        acc.x += w * yh.x; acc.y += w * yh.y; acc.z += w * yh.z; acc.w += w * yh.w;
        sea.x += w * ev.x; sea.y += w * ev.y; sea.z += w * ev.z; sea.w += w * ev.w;
    }
    for (int t = 64 + e16; t < deg; t += 16) {       // deg>64 fallback (rare)
        int4 mt = csrM[s + t];
        int r = mt.x;
        float sq = __int_as_float(mt.w);
        float nh = hn[(size_t)r * 8 + 4];
        float w = rsqrtf(fmaxf(nh + sq, 1e-24f));
        float4 yh = *(const float4*)(hn + (size_t)r * 8);
        float4 ev = *(const float4*)(ea + (size_t)mt.z * 16 + q * 4);
        acc.x += w * yh.x; acc.y += w * yh.y; acc.z += w * yh.z; acc.w += w * yh.w;
        sea.x += w * ev.x; sea.y += w * ev.y; sea.z += w * ev.z; sea.w += w * ev.w;
    }
    // reduce over the 16 edge-groups (lane bits 2..5); q columns stay separate
    #pragma unroll
    for (int mm = 4; mm <= 32; mm <<= 1) {
        acc.x += __shfl_xor(acc.x, mm, 64); acc.y += __shfl_xor(acc.y, mm, 64);
        acc.z += __shfl_xor(acc.z, mm, 64); acc.w += __shfl_xor(acc.w, mm, 64);
        sea.x += __shfl_xor(sea.x, mm, 64); sea.y += __shfl_xor(sea.y, mm, 64);
        sea.z += __shfl_xor(sea.z, mm, 64); sea.w += __shfl_xor(sea.w, mm, 64);
    }
    // per-lane partial of (sea @ W2e) for rows 4q..4q+3
    float4 pv;
    pv.x = sea.x*w2r0.x + sea.y*w2r1.x + sea.z*w2r2.x + sea.w*w2r3.x;
    pv.y = sea.x*w2r0.y + sea.y*w2r1.y + sea.z*w2r2.y + sea.w*w2r3.y;
    pv.z = sea.x*w2r0.z + sea.y*w2r1.z + sea.z*w2r2.z + sea.w*w2r3.z;
    pv.w = sea.x*w2r0.w + sea.y*w2r1.w + sea.z*w2r2.w + sea.w*w2r3.w;
    // combine the 4 q-partials
    #pragma unroll
    for (int mm = 1; mm <= 2; mm <<= 1) {
        pv.x += __shfl_xor(pv.x, mm, 64); pv.y += __shfl_xor(pv.y, mm, 64);
        pv.z += __shfl_xor(pv.z, mm, 64); pv.w += __shfl_xor(pv.w, mm, 64);
    }
    if (lane == 0) {
        float ic = 1.0f / fmaxf((float)deg, 1.0f);
        float4 o;
        o.x = (acc.x + pv.x) * ic + b2[0];
        o.y = (acc.y + pv.y) * ic + b2[1];
        o.z = (acc.z + pv.z) * ic + b2[2];
        o.w = (acc.w + pv.w) * ic + b2[3];
        float ss = o.x*o.x + o.y*o.y + o.z*o.z + o.w*o.w;
        float inv = rsqrtf(fmaxf(ss, 1e-24f));
        float4 res;
        res.x = 1.0f / (1.0f + expf(-(o.x * inv)));
        res.y = 1.0f / (1.0f + expf(-(o.y * inv)));
        res.z = 1.0f / (1.0f + expf(-(o.z * inv)));
        res.w = 1.0f / (1.0f + expf(-(o.w * inv)));
        *(float4*)(out + (size_t)node * 4) = res;
    }
}

// ---------------- launch ----------------
extern "C" void kernel_launch(void* const* d_in, const int* in_sizes, int n_in,
                              void* d_out, int out_size, void* d_ws, size_t ws_size,
                              hipStream_t stream) {
    const float* x   = (const float*)d_in[0];
    const int*   ei  = (const int*)d_in[1];
    const float* ea  = (const float*)d_in[2];
    const float* W1  = (const float*)d_in[3];
    const float* b1  = (const float*)d_in[4];
    const float* W2  = (const float*)d_in[5];
    const float* b2  = (const float*)d_in[6];
    const int* row = ei;
    const int* col = ei + N_EDGES;
    float* out = (float*)d_out;

    char* ws = (char*)d_ws;
    size_t o = 0;
    auto carve = [&](size_t bytes) { char* p = ws + o; o = (o + bytes + 255) & ~(size_t)255; return p; };
    __half* y1h    = (__half*)carve((size_t)N_NODES * 128 * 2);  // 25.6 MB
    int4*   csrM   = (int4*)carve((size_t)N_EDGES * 16);         // 25.6 MB
    int*    cnt    = (int*)carve((size_t)N_NODES * 4);
    int*    off    = (int*)carve((size_t)(N_NODES + 1) * 4);
    int*    head   = (int*)carve((size_t)N_NODES * 4);
    float*  nx     = (float*)carve((size_t)N_NODES * 4);
    float*  hn     = (float*)carve((size_t)N_NODES * 8 * 4);     // {yh4, nh, pad3}
    int*    psum   = (int*)carve((size_t)NCHUNKS * 4);
    int*    coff   = (int*)carve((size_t)NCHUNKS * 4);
    (void)ws_size; (void)in_sizes; (void)n_in; (void)out_size;

    hipMemsetAsync(cnt, 0, (size_t)N_NODES * 4, stream);

    dim3 b256(256);
    hist<<<(N_EDGES + 255) / 256, b256, 0, stream>>>(col, cnt);
    gemm_y1h<<<(N_NODES + 63) / 64, b256, 0, stream>>>(x, W1, y1h, nx);

    scan_part<<<NCHUNKS, CHUNK, 0, stream>>>(cnt, psum);
    scan_top<<<1, 64, 0, stream>>>(psum, coff, off);
    scan_apply<<<NCHUNKS, CHUNK, 0, stream>>>(cnt, coff, off, head);
    scatter_e<<<(N_EDGES + 255) / 256, b256, 0, stream>>>(row, col, nx, ea, head, csrM);

    layer1<<<(N_NODES + 3) / 4, b256, 0, stream>>>(y1h, ea, csrM, off, W1, b1, W2, hn);
    layer2<<<(N_NODES + 3) / 4, b256, 0, stream>>>(csrM, ea, hn, off, W2, b2, out);
}